// Round 1
// baseline (401.806 us; speedup 1.0000x reference)
//
#include <hip/hip_runtime.h>
#include <math.h>

// CapsuleLayer dynamic routing, fully fused: one block per batch element.
// B=256, I=1152, D=8, C=10, O=16, NUM_ROUTING=3.
//
// Thread mapping (640 threads = 8 i_local groups x 80 (c,o2) workers):
//   il = tid/80 (i stride group), r = tid%80, c = r/8, o2 = r%8 (o pair)
// Each iteration processes CHUNK=32 i's (4 sub-i per thread).
// hat chunk lives in registers; agreement reduced over the 8 o2-lanes via
// shfl_xor (8-aligned groups never cross the 64-lane wave boundary).
// bias[i][c] persists in LDS across the 3 rounds. W streamed 3x per block.

#define B_ 256
#define I_ 1152
#define D_ 8
#define C_ 10
#define O_ 16
#define EPS_ 1e-7f

#define THREADS 640
#define ILG 8            // i_local groups
#define SUBI 4           // sub-i per thread per iteration
#define CHUNK (ILG*SUBI) // 32 i per iteration
#define NITER (I_/CHUNK) // 36

__global__ __launch_bounds__(THREADS) void capsule_routing_kernel(
    const float* __restrict__ x,   // [B, I, D]
    const float* __restrict__ W,   // [I, C, D, O]
    float* __restrict__ out)       // [B, C, O]
{
    __shared__ float bias[I_ * C_];        // 46080 B
    __shared__ float spart[ILG][C_ * O_];  // 5120 B
    __shared__ float sv[C_ * O_];          // s
    __shared__ float vv[C_ * O_];          // v (squash output)
    __shared__ float ech[CHUNK][C_];       // exp chunk
    __shared__ float scale[C_];

    const int b   = blockIdx.x;
    const int tid = threadIdx.x;

    // init bias = 0
    for (int j = tid; j < I_ * C_; j += THREADS) bias[j] = 0.0f;

    const int il = tid / 80;       // 0..7
    const int rr = tid % 80;
    const int c  = rr / 8;         // 0..9
    const int o2 = rr % 8;         // 0..7
    const int o0 = o2 * 2;

    const float* xb = x + (size_t)b * I_ * D_;
    const float2* W2 = (const float2*)W;   // W viewed as float2 along o

    __syncthreads();

    // ---------------- Pass 0: route = 1/C uniformly ----------------
    {
        float acc0 = 0.0f, acc1 = 0.0f;
        for (int it = 0; it < NITER; ++it) {
            #pragma unroll
            for (int sub = 0; sub < SUBI; ++sub) {
                const int i = it * CHUNK + sub * ILG + il;
                const float* xi = xb + i * D_;
                const float2* wp = W2 + (i * C_ + c) * (D_ * O_ / 2) + o2;
                float h0 = 0.0f, h1 = 0.0f;
                #pragma unroll
                for (int d = 0; d < D_; ++d) {
                    float2 w = wp[d * (O_ / 2)];
                    float xv = xi[d];
                    h0 = fmaf(xv, w.x, h0);
                    h1 = fmaf(xv, w.y, h1);
                }
                acc0 += h0; acc1 += h1;
            }
        }
        spart[il][c * O_ + o0]     = acc0;
        spart[il][c * O_ + o0 + 1] = acc1;
    }
    __syncthreads();
    if (tid < C_ * O_) {
        float s = 0.0f;
        #pragma unroll
        for (int k = 0; k < ILG; ++k) s += spart[k][tid];
        sv[tid] = s * (1.0f / C_);
    }
    __syncthreads();
    if (tid < C_) {
        float n2 = 0.0f;
        #pragma unroll
        for (int o = 0; o < O_; ++o) { float t = sv[tid * O_ + o]; n2 = fmaf(t, t, n2); }
        scale[tid] = n2 / ((1.0f + n2) * sqrtf(n2 + EPS_));
    }
    __syncthreads();
    if (tid < C_ * O_) vv[tid] = sv[tid] * scale[tid / O_];
    __syncthreads();

    // ---------------- Passes 1,2: agreement -> bias -> softmax -> s ----------------
    for (int pass = 1; pass < 3; ++pass) {
        float sa0 = 0.0f, sa1 = 0.0f;
        for (int it = 0; it < NITER; ++it) {
            float h0s[SUBI], h1s[SUBI];
            const float v0 = vv[c * O_ + o0];
            const float v1 = vv[c * O_ + o0 + 1];
            #pragma unroll
            for (int sub = 0; sub < SUBI; ++sub) {
                const int i = it * CHUNK + sub * ILG + il;
                const float* xi = xb + i * D_;
                const float2* wp = W2 + (i * C_ + c) * (D_ * O_ / 2) + o2;
                float h0 = 0.0f, h1 = 0.0f;
                #pragma unroll
                for (int d = 0; d < D_; ++d) {
                    float2 w = wp[d * (O_ / 2)];
                    float xv = xi[d];
                    h0 = fmaf(xv, w.x, h0);
                    h1 = fmaf(xv, w.y, h1);
                }
                h0s[sub] = h0; h1s[sub] = h1;
                // agreement partial over this thread's 2 o's
                float p = h0 * v0 + h1 * v1;
                // reduce over the 8 o2-lanes (8-aligned groups, same wave)
                p += __shfl_xor(p, 1);
                p += __shfl_xor(p, 2);
                p += __shfl_xor(p, 4);
                if (o2 == 0) bias[i * C_ + c] += p;
            }
            __syncthreads();
            // per-i softmax numerator: 320 threads, one (i, c') each
            if (tid < CHUNK * C_) {
                const int il2 = tid / C_, cc = tid % C_;
                const int i = it * CHUNK + il2;
                float m = -1e30f;
                #pragma unroll
                for (int k = 0; k < C_; ++k) m = fmaxf(m, bias[i * C_ + k]);
                ech[il2][cc] = __expf(bias[i * C_ + cc] - m);
            }
            __syncthreads();
            // consume: route = e/sum, accumulate s
            #pragma unroll
            for (int sub = 0; sub < SUBI; ++sub) {
                const int ic = sub * ILG + il;
                float sum = 0.0f;
                #pragma unroll
                for (int k = 0; k < C_; ++k) sum += ech[ic][k];
                const float route = ech[ic][c] / sum;
                sa0 = fmaf(route, h0s[sub], sa0);
                sa1 = fmaf(route, h1s[sub], sa1);
            }
            __syncthreads();  // protect ech before next iteration rewrites it
        }
        spart[il][c * O_ + o0]     = sa0;
        spart[il][c * O_ + o0 + 1] = sa1;
        __syncthreads();
        if (tid < C_ * O_) {
            float s = 0.0f;
            #pragma unroll
            for (int k = 0; k < ILG; ++k) s += spart[k][tid];
            sv[tid] = s;
        }
        __syncthreads();
        if (tid < C_) {
            float n2 = 0.0f;
            #pragma unroll
            for (int o = 0; o < O_; ++o) { float t = sv[tid * O_ + o]; n2 = fmaf(t, t, n2); }
            scale[tid] = n2 / ((1.0f + n2) * sqrtf(n2 + EPS_));
        }
        __syncthreads();
        if (tid < C_ * O_) vv[tid] = sv[tid] * scale[tid / O_];
        __syncthreads();
    }

    if (tid < C_ * O_) out[(size_t)b * C_ * O_ + tid] = vv[tid];
}

extern "C" void kernel_launch(void* const* d_in, const int* in_sizes, int n_in,
                              void* d_out, int out_size, void* d_ws, size_t ws_size,
                              hipStream_t stream) {
    (void)in_sizes; (void)n_in; (void)d_ws; (void)ws_size; (void)out_size;
    const float* x = (const float*)d_in[0];
    const float* W = (const float*)d_in[1];
    float* out = (float*)d_out;
    capsule_routing_kernel<<<B_, THREADS, 0, stream>>>(x, W, out);
}

// Round 2
// 356.278 us; speedup vs baseline: 1.1278x; 1.1278x over previous
//
#include <hip/hip_runtime.h>
#include <hip/hip_bf16.h>
#include <math.h>

// CapsuleLayer dynamic routing. Strategy: materialize hat[b,i,c,o] once (bf16,
// 94 MB in d_ws), then each routing round is a streaming pass over hat.
// Falls back to the fused single-kernel version if ws_size is too small.

#define B_ 256
#define I_ 1152
#define D_ 8
#define C_ 10
#define O_ 16
#define CO_ (C_*O_)   // 160
#define EPS_ 1e-7f

// K1 geometry: b-tiles of 32, i-chunks of 18
#define BT 32
#define NBT (B_/BT)    // 8
#define IC1 18
#define NIC1 (I_/IC1)  // 64
// K3/K5 geometry: i-chunks of 64
#define IC3 64
#define NIC3 (I_/IC3)  // 18

// ---------------------------------------------------------------------------
// K1: hat = einsum('bid,icdo->bico'), stored bf16; also partial s1 (route=1/C)
// block = 384 threads = two wave-aligned halves of 192 (160 active: co=c*16+o)
// halves process alternating i within the chunk. x read via wave-uniform
// scalar loads; W fragment per thread in VGPRs; stores coalesced over co.
// ---------------------------------------------------------------------------
__global__ __launch_bounds__(384) void k1_hat(
    const float* __restrict__ x,       // [B,I,D]
    const float* __restrict__ W,       // [I,C,D,O]
    __hip_bfloat16* __restrict__ hat,  // [B,I,CO]
    float* __restrict__ sPart1)        // [NIC1][B][CO]
{
    __shared__ float sred[BT][CO_];
    const int tid = threadIdx.x;
    const int h   = tid / 192;          // 0/1, wave-aligned (192 = 3 waves)
    const int ht  = tid % 192;
    const int co  = ht;
    const int c   = co / O_, o = co % O_;
    const int ic  = blockIdx.x;         // 0..63
    const int bt  = blockIdx.y;         // 0..7
    const int b0  = bt * BT;
    const int i0  = ic * IC1;
    const bool act = (co < CO_);

    float s1acc[BT];
    #pragma unroll
    for (int bb = 0; bb < BT; ++bb) s1acc[bb] = 0.0f;

    const int hs = __builtin_amdgcn_readfirstlane(h);  // wave-uniform half id

    for (int k = 0; k < IC1 / 2; ++k) {
        const int i = i0 + 2 * k + hs;
        float wv[D_];
        if (act) {
            const float* wp = W + ((size_t)i * C_ + c) * (D_ * O_) + o;
            #pragma unroll
            for (int d = 0; d < D_; ++d) wv[d] = wp[d * O_];
        }
        #pragma unroll 4
        for (int bb = 0; bb < BT; ++bb) {
            const float* xp = x + ((size_t)(b0 + bb) * I_ + i) * D_;
            float xv[D_];
            #pragma unroll
            for (int d = 0; d < D_; ++d) xv[d] = xp[d];   // uniform -> s_load
            if (act) {
                float hv = 0.0f;
                #pragma unroll
                for (int d = 0; d < D_; ++d) hv = fmaf(xv[d], wv[d], hv);
                hat[((size_t)(b0 + bb) * I_ + i) * CO_ + co] = __float2bfloat16(hv);
                s1acc[bb] += hv;
            }
        }
    }
    if (h == 1 && act) {
        #pragma unroll
        for (int bb = 0; bb < BT; ++bb) sred[bb][co] = s1acc[bb];
    }
    __syncthreads();
    if (h == 0 && act) {
        for (int bb = 0; bb < BT; ++bb)
            sPart1[((size_t)ic * B_ + (b0 + bb)) * CO_ + co] =
                s1acc[bb] + sred[bb][co];
    }
}

// ---------------------------------------------------------------------------
// K3/K5: one routing round. block=(i-chunk, b); 384 thr = two halves of 192.
// Per i: read hat row, p[c]=sum_o hat*v (shfl over o-group), bias' = bias+p,
// softmax over c (batched 8 i's between barriers), s += route*hat.
// ---------------------------------------------------------------------------
template <int ROUND>
__global__ __launch_bounds__(384) void k_route(
    const __hip_bfloat16* __restrict__ hat,  // [B,I,CO]
    const float* __restrict__ v,             // [B,CO]  (v_{r-1})
    float* __restrict__ bias2,               // [B,I,C] written R2, read R3
    float* __restrict__ sPartR)              // [NIC3][B][CO]
{
    __shared__ float pbuf[2][8][C_];
    __shared__ float ebuf[2][8][C_];
    __shared__ float sred[CO_];
    const int tid = threadIdx.x;
    const int h = tid / 192, ht = tid % 192;
    const int co = ht, c = co / O_, o = co % O_;
    const int ic = blockIdx.x;   // 0..17
    const int b  = blockIdx.y;   // 0..255
    const int i0 = ic * IC3;
    const bool act = (co < CO_);

    const float vreg = act ? v[(size_t)b * CO_ + co] : 0.0f;
    float sacc = 0.0f;

    for (int batch = 0; batch < IC3 / 16; ++batch) {   // 4 batches of 8 i/half
        float hv[8];
        // phase 1: load hat, agreement p[c], bias', stage into pbuf
        for (int j = 0; j < 8; ++j) {
            const int i = i0 + (batch * 8 + j) * 2 + h;
            float pp = 0.0f;
            if (act) {
                hv[j] = __bfloat162float(hat[((size_t)b * I_ + i) * CO_ + co]);
                pp = hv[j] * vreg;
            }
            pp += __shfl_xor(pp, 1);
            pp += __shfl_xor(pp, 2);
            pp += __shfl_xor(pp, 4);
            pp += __shfl_xor(pp, 8);
            if (act && o == 0) {
                if (ROUND == 2) {
                    bias2[((size_t)b * I_ + i) * C_ + c] = pp;
                    pbuf[h][j][c] = pp;
                } else {
                    pbuf[h][j][c] = pp + bias2[((size_t)b * I_ + i) * C_ + c];
                }
            }
        }
        __syncthreads();
        // phase 2: 80 exps per half (one per (i_local, c))
        if (ht < 8 * C_) {
            const int j2 = ht / C_, cc = ht % C_;
            float m = pbuf[h][j2][0];
            #pragma unroll
            for (int q = 1; q < C_; ++q) m = fmaxf(m, pbuf[h][j2][q]);
            ebuf[h][j2][cc] = __expf(pbuf[h][j2][cc] - m);
        }
        __syncthreads();
        // phase 3: route = e/sum, accumulate s
        if (act) {
            #pragma unroll
            for (int j = 0; j < 8; ++j) {
                float sum = 0.0f;
                #pragma unroll
                for (int q = 0; q < C_; ++q) sum += ebuf[h][j][q];
                sacc = fmaf(ebuf[h][j][c] / sum, hv[j], sacc);
            }
        }
        // no barrier needed here: next phase-1 writes pbuf only, and the
        // barrier after it orders those writes vs this batch's ebuf reads
    }
    if (h == 1 && act) sred[co] = sacc;
    __syncthreads();
    if (h == 0 && act)
        sPartR[((size_t)ic * B_ + b) * CO_ + co] = sacc + sred[co];
}

// ---------------------------------------------------------------------------
// K2/K4/K6: reduce partials over chunks, squash, write v (or final out)
// ---------------------------------------------------------------------------
__global__ __launch_bounds__(192) void k_squash(
    const float* __restrict__ sPart,   // [nchunk][B][CO]
    int nchunk, float scale,
    float* __restrict__ dst)           // [B,CO]
{
    const int b = blockIdx.x, co = threadIdx.x;
    if (co >= CO_) return;
    float s = 0.0f;
    for (int k = 0; k < nchunk; ++k)
        s += sPart[((size_t)k * B_ + b) * CO_ + co];
    s *= scale;
    float n2 = s * s;
    n2 += __shfl_xor(n2, 1);
    n2 += __shfl_xor(n2, 2);
    n2 += __shfl_xor(n2, 4);
    n2 += __shfl_xor(n2, 8);
    const float sc = n2 / ((1.0f + n2) * sqrtf(n2 + EPS_));
    dst[(size_t)b * CO_ + co] = s * sc;
}

// ---------------------------------------------------------------------------
// Fallback: fully fused single kernel (R1 version, passes at ~402 us)
// ---------------------------------------------------------------------------
#define THREADS 640
#define ILG 8
#define SUBI 4
#define CHUNK (ILG*SUBI)
#define NITER (I_/CHUNK)

__global__ __launch_bounds__(THREADS) void capsule_routing_kernel(
    const float* __restrict__ x, const float* __restrict__ W,
    float* __restrict__ out)
{
    __shared__ float bias[I_ * C_];
    __shared__ float spart[ILG][C_ * O_];
    __shared__ float sv[C_ * O_];
    __shared__ float vv[C_ * O_];
    __shared__ float ech[CHUNK][C_];
    __shared__ float scale[C_];

    const int b   = blockIdx.x;
    const int tid = threadIdx.x;
    for (int j = tid; j < I_ * C_; j += THREADS) bias[j] = 0.0f;
    const int il = tid / 80;
    const int rr = tid % 80;
    const int c  = rr / 8;
    const int o2 = rr % 8;
    const int o0 = o2 * 2;
    const float* xb = x + (size_t)b * I_ * D_;
    const float2* W2 = (const float2*)W;
    __syncthreads();
    {
        float acc0 = 0.0f, acc1 = 0.0f;
        for (int it = 0; it < NITER; ++it) {
            #pragma unroll
            for (int sub = 0; sub < SUBI; ++sub) {
                const int i = it * CHUNK + sub * ILG + il;
                const float* xi = xb + i * D_;
                const float2* wp = W2 + (i * C_ + c) * (D_ * O_ / 2) + o2;
                float h0 = 0.0f, h1 = 0.0f;
                #pragma unroll
                for (int d = 0; d < D_; ++d) {
                    float2 w = wp[d * (O_ / 2)];
                    float xv = xi[d];
                    h0 = fmaf(xv, w.x, h0);
                    h1 = fmaf(xv, w.y, h1);
                }
                acc0 += h0; acc1 += h1;
            }
        }
        spart[il][c * O_ + o0]     = acc0;
        spart[il][c * O_ + o0 + 1] = acc1;
    }
    __syncthreads();
    if (tid < C_ * O_) {
        float s = 0.0f;
        #pragma unroll
        for (int k = 0; k < ILG; ++k) s += spart[k][tid];
        sv[tid] = s * (1.0f / C_);
    }
    __syncthreads();
    if (tid < C_) {
        float n2 = 0.0f;
        #pragma unroll
        for (int o = 0; o < O_; ++o) { float t = sv[tid * O_ + o]; n2 = fmaf(t, t, n2); }
        scale[tid] = n2 / ((1.0f + n2) * sqrtf(n2 + EPS_));
    }
    __syncthreads();
    if (tid < C_ * O_) vv[tid] = sv[tid] * scale[tid / O_];
    __syncthreads();
    for (int pass = 1; pass < 3; ++pass) {
        float sa0 = 0.0f, sa1 = 0.0f;
        for (int it = 0; it < NITER; ++it) {
            float h0s[SUBI], h1s[SUBI];
            const float v0 = vv[c * O_ + o0];
            const float v1 = vv[c * O_ + o0 + 1];
            #pragma unroll
            for (int sub = 0; sub < SUBI; ++sub) {
                const int i = it * CHUNK + sub * ILG + il;
                const float* xi = xb + i * D_;
                const float2* wp = W2 + (i * C_ + c) * (D_ * O_ / 2) + o2;
                float h0 = 0.0f, h1 = 0.0f;
                #pragma unroll
                for (int d = 0; d < D_; ++d) {
                    float2 w = wp[d * (O_ / 2)];
                    float xv = xi[d];
                    h0 = fmaf(xv, w.x, h0);
                    h1 = fmaf(xv, w.y, h1);
                }
                h0s[sub] = h0; h1s[sub] = h1;
                float p = h0 * v0 + h1 * v1;
                p += __shfl_xor(p, 1);
                p += __shfl_xor(p, 2);
                p += __shfl_xor(p, 4);
                if (o2 == 0) bias[i * C_ + c] += p;
            }
            __syncthreads();
            if (tid < CHUNK * C_) {
                const int il2 = tid / C_, cc = tid % C_;
                const int i = it * CHUNK + il2;
                float m = -1e30f;
                #pragma unroll
                for (int k = 0; k < C_; ++k) m = fmaxf(m, bias[i * C_ + k]);
                ech[il2][cc] = __expf(bias[i * C_ + cc] - m);
            }
            __syncthreads();
            #pragma unroll
            for (int sub = 0; sub < SUBI; ++sub) {
                const int icx = sub * ILG + il;
                float sum = 0.0f;
                #pragma unroll
                for (int k = 0; k < C_; ++k) sum += ech[icx][k];
                const float route = ech[icx][c] / sum;
                sa0 = fmaf(route, h0s[sub], sa0);
                sa1 = fmaf(route, h1s[sub], sa1);
            }
            __syncthreads();
        }
        spart[il][c * O_ + o0]     = sa0;
        spart[il][c * O_ + o0 + 1] = sa1;
        __syncthreads();
        if (tid < C_ * O_) {
            float s = 0.0f;
            #pragma unroll
            for (int k = 0; k < ILG; ++k) s += spart[k][tid];
            sv[tid] = s;
        }
        __syncthreads();
        if (tid < C_) {
            float n2 = 0.0f;
            #pragma unroll
            for (int o = 0; o < O_; ++o) { float t = sv[tid * O_ + o]; n2 = fmaf(t, t, n2); }
            scale[tid] = n2 / ((1.0f + n2) * sqrtf(n2 + EPS_));
        }
        __syncthreads();
        if (tid < C_ * O_) vv[tid] = sv[tid] * scale[tid / O_];
        __syncthreads();
    }
    if (tid < C_ * O_) out[(size_t)b * C_ * O_ + tid] = vv[tid];
}

// ---------------------------------------------------------------------------
extern "C" void kernel_launch(void* const* d_in, const int* in_sizes, int n_in,
                              void* d_out, int out_size, void* d_ws, size_t ws_size,
                              hipStream_t stream) {
    (void)in_sizes; (void)n_in; (void)out_size;
    const float* x = (const float*)d_in[0];
    const float* W = (const float*)d_in[1];
    float* out = (float*)d_out;

    const size_t hat_b   = (size_t)B_ * I_ * CO_ * sizeof(__hip_bfloat16); // 94.4 MB
    const size_t sp1_b   = (size_t)NIC1 * B_ * CO_ * sizeof(float);        // 10.5 MB
    const size_t bias_b  = (size_t)B_ * I_ * C_ * sizeof(float);           // 11.8 MB
    const size_t spr_b   = (size_t)NIC3 * B_ * CO_ * sizeof(float);        //  2.9 MB
    const size_t v_b     = (size_t)B_ * CO_ * sizeof(float);               //  160 KB
    const size_t need    = hat_b + sp1_b + bias_b + spr_b + v_b;

    if (ws_size >= need) {
        char* p = (char*)d_ws;
        __hip_bfloat16* hat = (__hip_bfloat16*)p;  p += hat_b;
        float* sPart1 = (float*)p;                 p += sp1_b;
        float* bias2  = (float*)p;                 p += bias_b;
        float* sPartR = (float*)p;                 p += spr_b;
        float* v      = (float*)p;

        k1_hat<<<dim3(NIC1, NBT), 384, 0, stream>>>(x, W, hat, sPart1);
        k_squash<<<B_, 192, 0, stream>>>(sPart1, NIC1, 1.0f / C_, v);
        k_route<2><<<dim3(NIC3, B_), 384, 0, stream>>>(hat, v, bias2, sPartR);
        k_squash<<<B_, 192, 0, stream>>>(sPartR, NIC3, 1.0f, v);
        k_route<3><<<dim3(NIC3, B_), 384, 0, stream>>>(hat, v, bias2, sPartR);
        k_squash<<<B_, 192, 0, stream>>>(sPartR, NIC3, 1.0f, out);
    } else {
        capsule_routing_kernel<<<B_, THREADS, 0, stream>>>(x, W, out);
    }
}

// Round 3
// 105.495 us; speedup vs baseline: 3.8087x; 3.3772x over previous
//
#include <hip/hip_runtime.h>
#include <hip/hip_bf16.h>
#include <math.h>

// CapsuleLayer dynamic routing.
// Pipeline: k1 (hat = x·W, bf16, + round-1 partial sums) -> squash ->
// k_route<2> (agreement+softmax+weighted sum) -> squash -> k_route<3> -> squash.
// hat[B,I,CO] bf16 (94 MB) lives in d_ws; bias stored f16.

#define B_ 256
#define I_ 1152
#define D_ 8
#define C_ 10
#define O_ 16
#define CO_ (C_*O_)   // 160
#define EPS_ 1e-7f

// k1 geometry
#define IC1 16
#define NIC1 (I_/IC1)   // 72
#define BT 16
#define NBT (B_/BT)     // 16
#define T1 320          // 4 groups of 80 (c,o2)
// k_route geometry
#define IC3 64
#define NIC3 (I_/IC3)   // 18
#define T3 320          // 32 il x 10 c

// ---------------------------------------------------------------------------
// K1: hat[b,i,c,o] = sum_d x[b,i,d] W[i,c,d,o]  (bf16), plus round-1 partials.
// x tile staged in LDS (broadcast reads); W fragment per thread in VGPRs;
// packed bf16x2 stores. Thread: (ig 0..3, c 0..9, o2 0..7); ig covers 4 i's.
// ---------------------------------------------------------------------------
__global__ __launch_bounds__(T1) void k1_hat(
    const float* __restrict__ x,       // [B,I,D]
    const float* __restrict__ W,       // [I,C,D,O]
    __hip_bfloat16* __restrict__ hat,  // [B,I,CO]
    float* __restrict__ sPart1)        // [NIC1][B][CO]
{
    __shared__ float xs[BT * IC1 * D_];   // 8 KB
    __shared__ float sred[BT][CO_];       // 10.25 KB
    const int tid = threadIdx.x;
    const int ic = blockIdx.x, bt = blockIdx.y;
    const int i0 = ic * IC1, b0 = bt * BT;

    // cooperative x tile load (coalesced per-b rows of 512B)
    for (int j = tid; j < BT * IC1 * D_; j += T1) {
        const int bb = j / (IC1 * D_), r = j % (IC1 * D_);
        xs[j] = x[((size_t)(b0 + bb) * I_ + i0) * D_ + r];
    }
    __syncthreads();

    const int ig = tid / 80, r = tid % 80;
    const int c = r / 8, o2 = r % 8;

    float2 acc[BT];
    #pragma unroll
    for (int bb = 0; bb < BT; ++bb) acc[bb] = make_float2(0.0f, 0.0f);

    const float2* W2 = (const float2*)W;

    for (int k = 0; k < IC1 / 4; ++k) {
        const int il = ig * 4 + k;
        const int i = i0 + il;
        float2 wv[D_];
        const float2* wp = W2 + ((size_t)i * C_ + c) * (D_ * O_ / 2) + o2;
        #pragma unroll
        for (int d = 0; d < D_; ++d) wv[d] = wp[d * (O_ / 2)];
        #pragma unroll
        for (int bb = 0; bb < BT; ++bb) {
            const float* xp = &xs[(bb * IC1 + il) * D_];
            float h0 = 0.0f, h1 = 0.0f;
            #pragma unroll
            for (int d = 0; d < D_; ++d) {
                const float xv = xp[d];
                h0 = fmaf(xv, wv[d].x, h0);
                h1 = fmaf(xv, wv[d].y, h1);
            }
            acc[bb].x += h0; acc[bb].y += h1;
            *(__hip_bfloat162*)&hat[((size_t)(b0 + bb) * I_ + i) * CO_ + c * O_ + o2 * 2] =
                __float22bfloat162_rn(make_float2(h0, h1));
        }
    }

    // staged reduce over the 4 ig groups
    if (ig == 0) {
        #pragma unroll
        for (int bb = 0; bb < BT; ++bb) {
            sred[bb][c * O_ + o2 * 2]     = acc[bb].x;
            sred[bb][c * O_ + o2 * 2 + 1] = acc[bb].y;
        }
    }
    __syncthreads();
    #pragma unroll
    for (int g = 1; g < 4; ++g) {
        if (ig == g) {
            #pragma unroll
            for (int bb = 0; bb < BT; ++bb) {
                sred[bb][c * O_ + o2 * 2]     += acc[bb].x;
                sred[bb][c * O_ + o2 * 2 + 1] += acc[bb].y;
            }
        }
        __syncthreads();
    }
    if (tid < CO_) {
        for (int bb = 0; bb < BT; ++bb)
            sPart1[((size_t)ic * B_ + (b0 + bb)) * CO_ + tid] = sred[bb][tid];
    }
}

// ---------------------------------------------------------------------------
// K_route: one routing round. Thread = (il 0..31, c 0..9); 320 threads, all
// active, no shuffles. Per i: thread owns the full 16-o hat row in regs,
// computes agreement p serially, softmax via tiny LDS exchange (ONE exp and
// ONE rcp per (i,c)), accumulates s in regs; block reduce at the end.
// ---------------------------------------------------------------------------
template <int ROUND>
__global__ __launch_bounds__(T3) void k_route(
    const __hip_bfloat16* __restrict__ hat,  // [B,I,CO]
    const float* __restrict__ v,             // [B,CO]
    _Float16* __restrict__ bias2,            // [B,I,C] (written R2, read R3)
    float* __restrict__ sPartR)              // [NIC3][B][CO]
{
    __shared__ float pb[32][C_];
    __shared__ float eb[32][C_];
    __shared__ float sr[32][CO_ + 4];        // +4 pad: break 160%32==0 stride
    const int tid = threadIdx.x;
    const int il = tid / C_, c = tid % C_;
    const int ic = blockIdx.x, b = blockIdx.y;
    const int i0 = ic * IC3;

    float vr[O_];
    #pragma unroll
    for (int o = 0; o < O_; ++o) vr[o] = v[(size_t)b * CO_ + c * O_ + o];
    float sacc[O_];
    #pragma unroll
    for (int o = 0; o < O_; ++o) sacc[o] = 0.0f;

    for (int sb = 0; sb < IC3 / 32; ++sb) {
        const int i = i0 + sb * 32 + il;
        // 32B hat row: two uint4 loads; bf16->f32 via bit ops
        const uint4* hp = (const uint4*)&hat[((size_t)b * I_ + i) * CO_ + c * O_];
        const uint4 ha = hp[0], hb = hp[1];
        float hf[O_];
        {
            const unsigned u[8] = {ha.x, ha.y, ha.z, ha.w, hb.x, hb.y, hb.z, hb.w};
            #pragma unroll
            for (int q = 0; q < 8; ++q) {
                hf[2 * q]     = __uint_as_float(u[q] << 16);
                hf[2 * q + 1] = __uint_as_float(u[q] & 0xffff0000u);
            }
        }
        float p = 0.0f;
        #pragma unroll
        for (int o = 0; o < O_; ++o) p = fmaf(hf[o], vr[o], p);
        if (ROUND == 2) {
            bias2[((size_t)b * I_ + i) * C_ + c] = (_Float16)p;
        } else {
            p += (float)bias2[((size_t)b * I_ + i) * C_ + c];
        }
        pb[il][c] = p;
        __syncthreads();
        float m = pb[il][0];
        #pragma unroll
        for (int q = 1; q < C_; ++q) m = fmaxf(m, pb[il][q]);
        const float e = __expf(p - m);
        eb[il][c] = e;
        __syncthreads();
        float sum = 0.0f;
        #pragma unroll
        for (int q = 0; q < C_; ++q) sum += eb[il][q];
        const float route = e * __builtin_amdgcn_rcpf(sum);
        #pragma unroll
        for (int o = 0; o < O_; ++o) sacc[o] = fmaf(route, hf[o], sacc[o]);
        // next iteration's pb write is ordered vs this phase-2 read by the
        // barrier after it; eb likewise. No extra barrier needed here.
        __syncthreads();
    }

    #pragma unroll
    for (int o = 0; o < O_; ++o) sr[il][c * O_ + o] = sacc[o];
    __syncthreads();
    if (tid < CO_) {
        float s = 0.0f;
        #pragma unroll
        for (int k = 0; k < 32; ++k) s += sr[k][tid];
        sPartR[((size_t)ic * B_ + b) * CO_ + tid] = s;
    }
}

// ---------------------------------------------------------------------------
// K_squash: reduce partials over chunks, squash, write v (or final out)
// ---------------------------------------------------------------------------
__global__ __launch_bounds__(192) void k_squash(
    const float* __restrict__ sPart,   // [nchunk][B][CO]
    int nchunk, float scale,
    float* __restrict__ dst)           // [B,CO]
{
    const int b = blockIdx.x, co = threadIdx.x;
    if (co >= CO_) return;
    float s = 0.0f;
    for (int k = 0; k < nchunk; ++k)
        s += sPart[((size_t)k * B_ + b) * CO_ + co];
    s *= scale;
    float n2 = s * s;
    n2 += __shfl_xor(n2, 1);
    n2 += __shfl_xor(n2, 2);
    n2 += __shfl_xor(n2, 4);
    n2 += __shfl_xor(n2, 8);
    const float sc = n2 / ((1.0f + n2) * sqrtf(n2 + EPS_));
    dst[(size_t)b * CO_ + co] = s * sc;
}

// ---------------------------------------------------------------------------
// Fallback: fully fused single kernel (R1 version, passes at ~402 us)
// ---------------------------------------------------------------------------
#define THREADS 640
#define ILG 8
#define SUBI 4
#define CHUNK (ILG*SUBI)
#define NITER (I_/CHUNK)

__global__ __launch_bounds__(THREADS) void capsule_routing_kernel(
    const float* __restrict__ x, const float* __restrict__ W,
    float* __restrict__ out)
{
    __shared__ float bias[I_ * C_];
    __shared__ float spart[ILG][C_ * O_];
    __shared__ float sv[C_ * O_];
    __shared__ float vv[C_ * O_];
    __shared__ float ech[CHUNK][C_];
    __shared__ float scale[C_];

    const int b   = blockIdx.x;
    const int tid = threadIdx.x;
    for (int j = tid; j < I_ * C_; j += THREADS) bias[j] = 0.0f;
    const int il = tid / 80;
    const int rr = tid % 80;
    const int c  = rr / 8;
    const int o2 = rr % 8;
    const int o0 = o2 * 2;
    const float* xb = x + (size_t)b * I_ * D_;
    const float2* W2 = (const float2*)W;
    __syncthreads();
    {
        float acc0 = 0.0f, acc1 = 0.0f;
        for (int it = 0; it < NITER; ++it) {
            #pragma unroll
            for (int sub = 0; sub < SUBI; ++sub) {
                const int i = it * CHUNK + sub * ILG + il;
                const float* xi = xb + i * D_;
                const float2* wp = W2 + (i * C_ + c) * (D_ * O_ / 2) + o2;
                float h0 = 0.0f, h1 = 0.0f;
                #pragma unroll
                for (int d = 0; d < D_; ++d) {
                    float2 w = wp[d * (O_ / 2)];
                    float xv = xi[d];
                    h0 = fmaf(xv, w.x, h0);
                    h1 = fmaf(xv, w.y, h1);
                }
                acc0 += h0; acc1 += h1;
            }
        }
        spart[il][c * O_ + o0]     = acc0;
        spart[il][c * O_ + o0 + 1] = acc1;
    }
    __syncthreads();
    if (tid < C_ * O_) {
        float s = 0.0f;
        #pragma unroll
        for (int k = 0; k < ILG; ++k) s += spart[k][tid];
        sv[tid] = s * (1.0f / C_);
    }
    __syncthreads();
    if (tid < C_) {
        float n2 = 0.0f;
        #pragma unroll
        for (int o = 0; o < O_; ++o) { float t = sv[tid * O_ + o]; n2 = fmaf(t, t, n2); }
        scale[tid] = n2 / ((1.0f + n2) * sqrtf(n2 + EPS_));
    }
    __syncthreads();
    if (tid < C_ * O_) vv[tid] = sv[tid] * scale[tid / O_];
    __syncthreads();
    for (int pass = 1; pass < 3; ++pass) {
        float sa0 = 0.0f, sa1 = 0.0f;
        for (int it = 0; it < NITER; ++it) {
            float h0s[SUBI], h1s[SUBI];
            const float v0 = vv[c * O_ + o0];
            const float v1 = vv[c * O_ + o0 + 1];
            #pragma unroll
            for (int sub = 0; sub < SUBI; ++sub) {
                const int i = it * CHUNK + sub * ILG + il;
                const float* xi = xb + i * D_;
                const float2* wp = W2 + (i * C_ + c) * (D_ * O_ / 2) + o2;
                float h0 = 0.0f, h1 = 0.0f;
                #pragma unroll
                for (int d = 0; d < D_; ++d) {
                    float2 w = wp[d * (O_ / 2)];
                    float xv = xi[d];
                    h0 = fmaf(xv, w.x, h0);
                    h1 = fmaf(xv, w.y, h1);
                }
                h0s[sub] = h0; h1s[sub] = h1;
                float p = h0 * v0 + h1 * v1;
                p += __shfl_xor(p, 1);
                p += __shfl_xor(p, 2);
                p += __shfl_xor(p, 4);
                if (o2 == 0) bias[i * C_ + c] += p;
            }
            __syncthreads();
            if (tid < CHUNK * C_) {
                const int il2 = tid / C_, cc = tid % C_;
                const int i = it * CHUNK + il2;
                float m = -1e30f;
                #pragma unroll
                for (int k = 0; k < C_; ++k) m = fmaxf(m, bias[i * C_ + k]);
                ech[il2][cc] = __expf(bias[i * C_ + cc] - m);
            }
            __syncthreads();
            #pragma unroll
            for (int sub = 0; sub < SUBI; ++sub) {
                const int icx = sub * ILG + il;
                float sum = 0.0f;
                #pragma unroll
                for (int k = 0; k < C_; ++k) sum += ech[icx][k];
                const float route = ech[icx][c] / sum;
                sa0 = fmaf(route, h0s[sub], sa0);
                sa1 = fmaf(route, h1s[sub], sa1);
            }
            __syncthreads();
        }
        spart[il][c * O_ + o0]     = sa0;
        spart[il][c * O_ + o0 + 1] = sa1;
        __syncthreads();
        if (tid < C_ * O_) {
            float s = 0.0f;
            #pragma unroll
            for (int k = 0; k < ILG; ++k) s += spart[k][tid];
            sv[tid] = s;
        }
        __syncthreads();
        if (tid < C_) {
            float n2 = 0.0f;
            #pragma unroll
            for (int o = 0; o < O_; ++o) { float t = sv[tid * O_ + o]; n2 = fmaf(t, t, n2); }
            scale[tid] = n2 / ((1.0f + n2) * sqrtf(n2 + EPS_));
        }
        __syncthreads();
        if (tid < C_ * O_) vv[tid] = sv[tid] * scale[tid / O_];
        __syncthreads();
    }
    if (tid < C_ * O_) out[(size_t)b * C_ * O_ + tid] = vv[tid];
}

// ---------------------------------------------------------------------------
extern "C" void kernel_launch(void* const* d_in, const int* in_sizes, int n_in,
                              void* d_out, int out_size, void* d_ws, size_t ws_size,
                              hipStream_t stream) {
    (void)in_sizes; (void)n_in; (void)out_size;
    const float* x = (const float*)d_in[0];
    const float* W = (const float*)d_in[1];
    float* out = (float*)d_out;

    const size_t hat_b  = (size_t)B_ * I_ * CO_ * sizeof(__hip_bfloat16); // 94.4 MB
    const size_t sp1_b  = (size_t)NIC1 * B_ * CO_ * sizeof(float);        // 11.8 MB
    const size_t bias_b = (size_t)B_ * I_ * C_ * sizeof(_Float16);        //  5.9 MB
    const size_t spr_b  = (size_t)NIC3 * B_ * CO_ * sizeof(float);        //  2.95 MB
    const size_t v_b    = (size_t)B_ * CO_ * sizeof(float);               //  160 KB
    const size_t need   = hat_b + sp1_b + bias_b + spr_b + v_b;           // ~115.2 MB

    if (ws_size >= need) {
        char* p = (char*)d_ws;
        __hip_bfloat16* hat = (__hip_bfloat16*)p;  p += hat_b;
        float* sPart1 = (float*)p;                 p += sp1_b;
        _Float16* bias2 = (_Float16*)p;            p += bias_b;
        float* sPartR = (float*)p;                 p += spr_b;
        float* v      = (float*)p;

        k1_hat<<<dim3(NIC1, NBT), T1, 0, stream>>>(x, W, hat, sPart1);
        k_squash<<<B_, 192, 0, stream>>>(sPart1, NIC1, 1.0f / C_, v);
        k_route<2><<<dim3(NIC3, B_), T3, 0, stream>>>(hat, v, bias2, sPartR);
        k_squash<<<B_, 192, 0, stream>>>(sPartR, NIC3, 1.0f, v);
        k_route<3><<<dim3(NIC3, B_), T3, 0, stream>>>(hat, v, bias2, sPartR);
        k_squash<<<B_, 192, 0, stream>>>(sPartR, NIC3, 1.0f, out);
    } else {
        capsule_routing_kernel<<<B_, THREADS, 0, stream>>>(x, W, out);
    }
}

// Round 4
// 96.005 us; speedup vs baseline: 4.1852x; 1.0988x over previous
//
#include <hip/hip_runtime.h>
#include <hip/hip_bf16.h>
#include <math.h>

// CapsuleLayer dynamic routing.
// k1 (hat = x·W -> bf16 in ws, + round-1 partials) -> squash -> k_route<2>
// -> squash -> k_route<3> -> squash(out). hat[B,I,CO] bf16 = 94 MB in d_ws.

#define B_ 256
#define I_ 1152
#define D_ 8
#define C_ 10
#define O_ 16
#define CO_ (C_*O_)   // 160
#define EPS_ 1e-7f

// k1 geometry
#define IC1 16
#define NIC1 (I_/IC1)   // 72
#define BT 32
#define NBT (B_/BT)     // 8  (W re-read = 5.9 MB * NBT = 47 MB)
#define T1 320          // 4 ig groups x 80 (c,o2)
// k_route geometry
#define IC3 128
#define NIC3 (I_/IC3)   // 9
#define T3 320          // 32 il x 10 c

// ---------------------------------------------------------------------------
// K1: hat[b,i,c,o] = sum_d x[b,i,d] W[i,c,d,o]  (bf16), plus round-1 partials.
// x tile in LDS (broadcast reads); W fragment in VGPRs; bf16x2 packed stores.
// Thread: (ig 0..3, c 0..9, o2 0..7); ig covers IC1/4 i's; BT=32 b's inner.
// ---------------------------------------------------------------------------
__global__ __launch_bounds__(T1) void k1_hat(
    const float* __restrict__ x,       // [B,I,D]
    const float* __restrict__ W,       // [I,C,D,O]
    __hip_bfloat16* __restrict__ hat,  // [B,I,CO]
    float* __restrict__ sPart1)        // [NIC1][B][CO]
{
    __shared__ float xs[BT * IC1 * D_];   // 16 KB
    __shared__ float sred[BT][CO_];       // 20 KB
    const int tid = threadIdx.x;
    const int ic = blockIdx.x, bt = blockIdx.y;
    const int i0 = ic * IC1, b0 = bt * BT;

    // cooperative x tile load (512B contiguous per b row)
    for (int j = tid; j < BT * IC1 * D_; j += T1) {
        const int bb = j / (IC1 * D_), r = j % (IC1 * D_);
        xs[j] = x[((size_t)(b0 + bb) * I_ + i0) * D_ + r];
    }
    __syncthreads();

    const int ig = tid / 80, r = tid % 80;
    const int c = r / 8, o2 = r % 8;

    float2 acc[BT];
    #pragma unroll
    for (int bb = 0; bb < BT; ++bb) acc[bb] = make_float2(0.0f, 0.0f);

    const float2* W2 = (const float2*)W;

    for (int k = 0; k < IC1 / 4; ++k) {
        const int il = ig * (IC1 / 4) + k;
        const int i = i0 + il;
        float2 wv[D_];
        const float2* wp = W2 + ((size_t)i * C_ + c) * (D_ * O_ / 2) + o2;
        #pragma unroll
        for (int d = 0; d < D_; ++d) wv[d] = wp[d * (O_ / 2)];
        #pragma unroll
        for (int bb = 0; bb < BT; ++bb) {
            const float* xp = &xs[(bb * IC1 + il) * D_];
            float h0 = 0.0f, h1 = 0.0f;
            #pragma unroll
            for (int d = 0; d < D_; ++d) {
                const float xv = xp[d];
                h0 = fmaf(xv, wv[d].x, h0);
                h1 = fmaf(xv, wv[d].y, h1);
            }
            acc[bb].x += h0; acc[bb].y += h1;
            *(__hip_bfloat162*)&hat[((size_t)(b0 + bb) * I_ + i) * CO_ + c * O_ + o2 * 2] =
                __float22bfloat162_rn(make_float2(h0, h1));
        }
    }

    // staged reduce over the 4 ig groups
    if (ig == 0) {
        #pragma unroll
        for (int bb = 0; bb < BT; ++bb) {
            sred[bb][c * O_ + o2 * 2]     = acc[bb].x;
            sred[bb][c * O_ + o2 * 2 + 1] = acc[bb].y;
        }
    }
    __syncthreads();
    #pragma unroll
    for (int g = 1; g < 4; ++g) {
        if (ig == g) {
            #pragma unroll
            for (int bb = 0; bb < BT; ++bb) {
                sred[bb][c * O_ + o2 * 2]     += acc[bb].x;
                sred[bb][c * O_ + o2 * 2 + 1] += acc[bb].y;
            }
        }
        __syncthreads();
    }
    if (tid < CO_) {
        for (int bb = 0; bb < BT; ++bb)
            sPart1[((size_t)ic * B_ + (b0 + bb)) * CO_ + tid] = sred[bb][tid];
    }
}

// ---------------------------------------------------------------------------
// K_route: one routing round. Thread = (il 0..31, c 0..9); all active.
// Per 32-i batch: write p to pb, 1 barrier, LOCAL softmax (10 exps, identical
// order per il => deterministic), accumulate s in regs, 1 barrier (WAR).
// bias2 layout [B][C][I] for contiguous runs over il.
// ---------------------------------------------------------------------------
template <int ROUND>
__global__ __launch_bounds__(T3) void k_route(
    const __hip_bfloat16* __restrict__ hat,  // [B,I,CO]
    const float* __restrict__ v,             // [B,CO]
    _Float16* __restrict__ bias2,            // [B][C][I]
    float* __restrict__ sPartR)              // [NIC3][B][CO]
{
    __shared__ float pb[32][C_];
    __shared__ float sr[32][CO_ + 4];
    const int tid = threadIdx.x;
    const int il = tid / C_, c = tid % C_;
    const int ic = blockIdx.x, b = blockIdx.y;
    const int i0 = ic * IC3;

    float vr[O_];
    #pragma unroll
    for (int o = 0; o < O_; ++o) vr[o] = v[(size_t)b * CO_ + c * O_ + o];
    float sacc[O_];
    #pragma unroll
    for (int o = 0; o < O_; ++o) sacc[o] = 0.0f;

    for (int sb = 0; sb < IC3 / 32; ++sb) {   // 4 batches, 1 i per thread each
        const int i = i0 + sb * 32 + il;
        // 32B hat row: two uint4 loads; bf16->f32 via bit ops
        const uint4* hp = (const uint4*)&hat[((size_t)b * I_ + i) * CO_ + c * O_];
        const uint4 ha = hp[0], hb = hp[1];
        float hf[O_];
        {
            const unsigned u[8] = {ha.x, ha.y, ha.z, ha.w, hb.x, hb.y, hb.z, hb.w};
            #pragma unroll
            for (int q = 0; q < 8; ++q) {
                hf[2 * q]     = __uint_as_float(u[q] << 16);
                hf[2 * q + 1] = __uint_as_float(u[q] & 0xffff0000u);
            }
        }
        float p = 0.0f;
        #pragma unroll
        for (int o = 0; o < O_; ++o) p = fmaf(hf[o], vr[o], p);
        if (ROUND == 2) {
            bias2[((size_t)b * C_ + c) * I_ + i] = (_Float16)p;
        } else {
            p += (float)bias2[((size_t)b * C_ + c) * I_ + i];
        }
        pb[il][c] = p;
        __syncthreads();
        // local softmax over the 10 logits of row il
        float pv[C_];
        #pragma unroll
        for (int q = 0; q < C_; ++q) pv[q] = pb[il][q];
        float m = pv[0];
        #pragma unroll
        for (int q = 1; q < C_; ++q) m = fmaxf(m, pv[q]);
        float sum = 0.0f;
        #pragma unroll
        for (int q = 0; q < C_; ++q) sum += __expf(pv[q] - m);
        const float route = __expf(p - m) * __builtin_amdgcn_rcpf(sum);
        #pragma unroll
        for (int o = 0; o < O_; ++o) sacc[o] = fmaf(route, hf[o], sacc[o]);
        __syncthreads();   // WAR: pb overwritten next batch
    }

    #pragma unroll
    for (int o = 0; o < O_; ++o) sr[il][c * O_ + o] = sacc[o];
    __syncthreads();
    if (tid < CO_) {
        float s = 0.0f;
        #pragma unroll
        for (int k = 0; k < 32; ++k) s += sr[k][tid];
        sPartR[((size_t)ic * B_ + b) * CO_ + tid] = s;
    }
}

// ---------------------------------------------------------------------------
// K_squash: reduce partials over chunks (4-way split), squash, write dst.
// ---------------------------------------------------------------------------
__global__ __launch_bounds__(640) void k_squash(
    const float* __restrict__ sPart,   // [nchunk][B][CO]
    int nchunk, float scale,
    float* __restrict__ dst)           // [B,CO]
{
    __shared__ float red[4][CO_];
    const int b = blockIdx.x, tid = threadIdx.x;
    const int q = tid / CO_;           // 0..3
    const int co = tid % CO_;
    float s = 0.0f;
    for (int k = q; k < nchunk; k += 4)
        s += sPart[((size_t)k * B_ + b) * CO_ + co];
    red[q][co] = s;
    __syncthreads();
    if (tid < CO_) {
        s = (red[0][co] + red[1][co]) + (red[2][co] + red[3][co]);
        s *= scale;
        float n2 = s * s;
        n2 += __shfl_xor(n2, 1);
        n2 += __shfl_xor(n2, 2);
        n2 += __shfl_xor(n2, 4);
        n2 += __shfl_xor(n2, 8);
        const float sc = n2 / ((1.0f + n2) * sqrtf(n2 + EPS_));
        dst[(size_t)b * CO_ + co] = s * sc;
    }
}

// ---------------------------------------------------------------------------
// Fallback: fully fused single kernel (R1 version, ~402 us) if ws too small
// ---------------------------------------------------------------------------
#define THREADS 640
#define ILG 8
#define SUBI 4
#define CHUNK (ILG*SUBI)
#define NITER (I_/CHUNK)

__global__ __launch_bounds__(THREADS) void capsule_routing_kernel(
    const float* __restrict__ x, const float* __restrict__ W,
    float* __restrict__ out)
{
    __shared__ float bias[I_ * C_];
    __shared__ float spart[ILG][C_ * O_];
    __shared__ float sv[C_ * O_];
    __shared__ float vv[C_ * O_];
    __shared__ float ech[CHUNK][C_];
    __shared__ float scale[C_];

    const int b   = blockIdx.x;
    const int tid = threadIdx.x;
    for (int j = tid; j < I_ * C_; j += THREADS) bias[j] = 0.0f;
    const int il = tid / 80;
    const int rr = tid % 80;
    const int c  = rr / 8;
    const int o2 = rr % 8;
    const int o0 = o2 * 2;
    const float* xb = x + (size_t)b * I_ * D_;
    const float2* W2 = (const float2*)W;
    __syncthreads();
    {
        float acc0 = 0.0f, acc1 = 0.0f;
        for (int it = 0; it < NITER; ++it) {
            #pragma unroll
            for (int sub = 0; sub < SUBI; ++sub) {
                const int i = it * CHUNK + sub * ILG + il;
                const float* xi = xb + i * D_;
                const float2* wp = W2 + (i * C_ + c) * (D_ * O_ / 2) + o2;
                float h0 = 0.0f, h1 = 0.0f;
                #pragma unroll
                for (int d = 0; d < D_; ++d) {
                    float2 w = wp[d * (O_ / 2)];
                    float xv = xi[d];
                    h0 = fmaf(xv, w.x, h0);
                    h1 = fmaf(xv, w.y, h1);
                }
                acc0 += h0; acc1 += h1;
            }
        }
        spart[il][c * O_ + o0]     = acc0;
        spart[il][c * O_ + o0 + 1] = acc1;
    }
    __syncthreads();
    if (tid < C_ * O_) {
        float s = 0.0f;
        #pragma unroll
        for (int k = 0; k < ILG; ++k) s += spart[k][tid];
        sv[tid] = s * (1.0f / C_);
    }
    __syncthreads();
    if (tid < C_) {
        float n2 = 0.0f;
        #pragma unroll
        for (int o = 0; o < O_; ++o) { float t = sv[tid * O_ + o]; n2 = fmaf(t, t, n2); }
        scale[tid] = n2 / ((1.0f + n2) * sqrtf(n2 + EPS_));
    }
    __syncthreads();
    if (tid < C_ * O_) vv[tid] = sv[tid] * scale[tid / O_];
    __syncthreads();
    for (int pass = 1; pass < 3; ++pass) {
        float sa0 = 0.0f, sa1 = 0.0f;
        for (int it = 0; it < NITER; ++it) {
            float h0s[SUBI], h1s[SUBI];
            const float v0 = vv[c * O_ + o0];
            const float v1 = vv[c * O_ + o0 + 1];
            #pragma unroll
            for (int sub = 0; sub < SUBI; ++sub) {
                const int i = it * CHUNK + sub * ILG + il;
                const float* xi = xb + i * D_;
                const float2* wp = W2 + (i * C_ + c) * (D_ * O_ / 2) + o2;
                float h0 = 0.0f, h1 = 0.0f;
                #pragma unroll
                for (int d = 0; d < D_; ++d) {
                    float2 w = wp[d * (O_ / 2)];
                    float xv = xi[d];
                    h0 = fmaf(xv, w.x, h0);
                    h1 = fmaf(xv, w.y, h1);
                }
                h0s[sub] = h0; h1s[sub] = h1;
                float p = h0 * v0 + h1 * v1;
                p += __shfl_xor(p, 1);
                p += __shfl_xor(p, 2);
                p += __shfl_xor(p, 4);
                if (o2 == 0) bias[i * C_ + c] += p;
            }
            __syncthreads();
            if (tid < CHUNK * C_) {
                const int il2 = tid / C_, cc = tid % C_;
                const int i = it * CHUNK + il2;
                float m = -1e30f;
                #pragma unroll
                for (int k = 0; k < C_; ++k) m = fmaxf(m, bias[i * C_ + k]);
                ech[il2][cc] = __expf(bias[i * C_ + cc] - m);
            }
            __syncthreads();
            #pragma unroll
            for (int sub = 0; sub < SUBI; ++sub) {
                const int icx = sub * ILG + il;
                float sum = 0.0f;
                #pragma unroll
                for (int k = 0; k < C_; ++k) sum += ech[icx][k];
                const float route = ech[icx][c] / sum;
                sa0 = fmaf(route, h0s[sub], sa0);
                sa1 = fmaf(route, h1s[sub], sa1);
            }
            __syncthreads();
        }
        spart[il][c * O_ + o0]     = sa0;
        spart[il][c * O_ + o0 + 1] = sa1;
        __syncthreads();
        if (tid < C_ * O_) {
            float s = 0.0f;
            #pragma unroll
            for (int k = 0; k < ILG; ++k) s += spart[k][tid];
            sv[tid] = s;
        }
        __syncthreads();
        if (tid < C_) {
            float n2 = 0.0f;
            #pragma unroll
            for (int o = 0; o < O_; ++o) { float t = sv[tid * O_ + o]; n2 = fmaf(t, t, n2); }
            scale[tid] = n2 / ((1.0f + n2) * sqrtf(n2 + EPS_));
        }
        __syncthreads();
        if (tid < C_ * O_) vv[tid] = sv[tid] * scale[tid / O_];
        __syncthreads();
    }
    if (tid < C_ * O_) out[(size_t)b * C_ * O_ + tid] = vv[tid];
}

// ---------------------------------------------------------------------------
extern "C" void kernel_launch(void* const* d_in, const int* in_sizes, int n_in,
                              void* d_out, int out_size, void* d_ws, size_t ws_size,
                              hipStream_t stream) {
    (void)in_sizes; (void)n_in; (void)out_size;
    const float* x = (const float*)d_in[0];
    const float* W = (const float*)d_in[1];
    float* out = (float*)d_out;

    const size_t hat_b  = (size_t)B_ * I_ * CO_ * sizeof(__hip_bfloat16); // 94.4 MB
    const size_t sp1_b  = (size_t)NIC1 * B_ * CO_ * sizeof(float);        // 11.8 MB
    const size_t bias_b = (size_t)B_ * I_ * C_ * sizeof(_Float16);        //  5.9 MB
    const size_t spr_b  = (size_t)NIC3 * B_ * CO_ * sizeof(float);        //  1.5 MB
    const size_t v_b    = (size_t)B_ * CO_ * sizeof(float);               //  160 KB
    const size_t need   = hat_b + sp1_b + bias_b + spr_b + v_b;           // ~113.8 MB

    if (ws_size >= need) {
        char* p = (char*)d_ws;
        __hip_bfloat16* hat = (__hip_bfloat16*)p;  p += hat_b;
        float* sPart1 = (float*)p;                 p += sp1_b;
        _Float16* bias2 = (_Float16*)p;            p += bias_b;
        float* sPartR = (float*)p;                 p += spr_b;
        float* v      = (float*)p;

        k1_hat<<<dim3(NIC1, NBT), T1, 0, stream>>>(x, W, hat, sPart1);
        k_squash<<<B_, 640, 0, stream>>>(sPart1, NIC1, 1.0f / C_, v);
        k_route<2><<<dim3(NIC3, B_), T3, 0, stream>>>(hat, v, bias2, sPartR);
        k_squash<<<B_, 640, 0, stream>>>(sPartR, NIC3, 1.0f, v);
        k_route<3><<<dim3(NIC3, B_), T3, 0, stream>>>(hat, v, bias2, sPartR);
        k_squash<<<B_, 640, 0, stream>>>(sPartR, NIC3, 1.0f, out);
    } else {
        capsule_routing_kernel<<<B_, THREADS, 0, stream>>>(x, W, out);
    }
}

// Round 5
// 77.131 us; speedup vs baseline: 5.2094x; 1.2447x over previous
//
#include <hip/hip_runtime.h>
#include <hip/hip_bf16.h>
#include <math.h>

// CapsuleLayer dynamic routing.
// Key algebraic identity: routing bias after round r = hat · (v0+...+v_{r-1}),
// so no bias buffer is needed — each route pass takes veff = running sum of v.
// Pipeline: k1 (hat=x·W -> bf16 ws, + round-1 partials) -> squash(veff1=v0)
// -> route(veff1) -> squash(veff2=veff1+v1) -> route(veff2) -> squash(out=v2).

#define B_ 256
#define I_ 1152
#define D_ 8
#define C_ 10
#define O_ 16
#define CO_ (C_*O_)   // 160
#define EPS_ 1e-7f

// k1 geometry
#define IC1 16
#define NIC1 (I_/IC1)   // 72
#define BT 16
#define NBT (B_/BT)     // 16
#define T1 320          // 4 ig groups x 80 (c,o2)
// k_route geometry
#define IC3 128
#define NIC3 (I_/IC3)   // 9
#define T3 320          // 32 il x 10 c

// ---------------------------------------------------------------------------
// K1: hat[b,i,c,o] = sum_d x[b,i,d] W[i,c,d,o]  (bf16), plus round-1 partials.
// x tile in LDS (broadcast reads); W fragment in VGPRs; bf16x2 packed stores.
// Thread: (ig 0..3, c 0..9, o2 0..7); ig covers 4 i's; BT=16 b's inner.
// ---------------------------------------------------------------------------
__global__ __launch_bounds__(T1) void k1_hat(
    const float* __restrict__ x,       // [B,I,D]
    const float* __restrict__ W,       // [I,C,D,O]
    __hip_bfloat16* __restrict__ hat,  // [B,I,CO]
    float* __restrict__ sPart1)        // [NIC1][B][CO]
{
    __shared__ float xs[BT * IC1 * D_];   // 8 KB
    __shared__ float sred[BT][CO_];       // 10 KB
    const int tid = threadIdx.x;
    const int ic = blockIdx.x, bt = blockIdx.y;
    const int i0 = ic * IC1, b0 = bt * BT;

    // cooperative x tile load, float4 (rows are 32B-aligned: 8 floats/(b,i))
    for (int j = tid; j < BT * IC1 * D_ / 4; j += T1) {   // 512 float4
        const int bb = j >> 5, r = j & 31;
        ((float4*)xs)[j] =
            *(const float4*)&x[(((size_t)(b0 + bb)) * I_ + i0) * D_ + r * 4];
    }
    __syncthreads();

    const int ig = tid / 80, r = tid % 80;
    const int c = r / 8, o2 = r % 8;

    float2 acc[BT];
    #pragma unroll
    for (int bb = 0; bb < BT; ++bb) acc[bb] = make_float2(0.0f, 0.0f);

    const float2* W2 = (const float2*)W;

    for (int k = 0; k < IC1 / 4; ++k) {
        const int il = ig * (IC1 / 4) + k;
        const int i = i0 + il;
        float2 wv[D_];
        const float2* wp = W2 + ((size_t)i * C_ + c) * (D_ * O_ / 2) + o2;
        #pragma unroll
        for (int d = 0; d < D_; ++d) wv[d] = wp[d * (O_ / 2)];
        #pragma unroll
        for (int bb = 0; bb < BT; ++bb) {
            const float* xp = &xs[(bb * IC1 + il) * D_];
            float h0 = 0.0f, h1 = 0.0f;
            #pragma unroll
            for (int d = 0; d < D_; ++d) {
                const float xv = xp[d];
                h0 = fmaf(xv, wv[d].x, h0);
                h1 = fmaf(xv, wv[d].y, h1);
            }
            acc[bb].x += h0; acc[bb].y += h1;
            *(__hip_bfloat162*)&hat[((size_t)(b0 + bb) * I_ + i) * CO_ + c * O_ + o2 * 2] =
                __float22bfloat162_rn(make_float2(h0, h1));
        }
    }

    // staged reduce over the 4 ig groups
    if (ig == 0) {
        #pragma unroll
        for (int bb = 0; bb < BT; ++bb) {
            sred[bb][c * O_ + o2 * 2]     = acc[bb].x;
            sred[bb][c * O_ + o2 * 2 + 1] = acc[bb].y;
        }
    }
    __syncthreads();
    #pragma unroll
    for (int g = 1; g < 4; ++g) {
        if (ig == g) {
            #pragma unroll
            for (int bb = 0; bb < BT; ++bb) {
                sred[bb][c * O_ + o2 * 2]     += acc[bb].x;
                sred[bb][c * O_ + o2 * 2 + 1] += acc[bb].y;
            }
        }
        __syncthreads();
    }
    if (tid < CO_) {
        for (int bb = 0; bb < BT; ++bb)
            sPart1[((size_t)ic * B_ + (b0 + bb)) * CO_ + tid] = sred[bb][tid];
    }
}

// ---------------------------------------------------------------------------
// K_route: one routing round. Thread = (il 0..31, c 0..9); all active.
// logits = hat · veff (veff = sum of all previous v's — exact bias, f32).
// Per 32-i batch: p -> pb, 1 barrier, local softmax (deterministic), s in
// regs, 1 barrier (WAR). Block-reduce at the end.
// ---------------------------------------------------------------------------
__global__ __launch_bounds__(T3) void k_route(
    const __hip_bfloat16* __restrict__ hat,  // [B,I,CO]
    const float* __restrict__ veff,          // [B,CO]
    float* __restrict__ sPartR)              // [NIC3][B][CO]
{
    __shared__ float pb[32][C_];
    __shared__ float sr[32][CO_ + 4];
    const int tid = threadIdx.x;
    const int il = tid / C_, c = tid % C_;
    const int ic = blockIdx.x, b = blockIdx.y;
    const int i0 = ic * IC3;

    float vr[O_];
    #pragma unroll
    for (int o = 0; o < O_; ++o) vr[o] = veff[(size_t)b * CO_ + c * O_ + o];
    float sacc[O_];
    #pragma unroll
    for (int o = 0; o < O_; ++o) sacc[o] = 0.0f;

    for (int sb = 0; sb < IC3 / 32; ++sb) {   // 4 batches, 1 i per thread each
        const int i = i0 + sb * 32 + il;
        const uint4* hp = (const uint4*)&hat[((size_t)b * I_ + i) * CO_ + c * O_];
        const uint4 ha = hp[0], hb = hp[1];
        float hf[O_];
        {
            const unsigned u[8] = {ha.x, ha.y, ha.z, ha.w, hb.x, hb.y, hb.z, hb.w};
            #pragma unroll
            for (int q = 0; q < 8; ++q) {
                hf[2 * q]     = __uint_as_float(u[q] << 16);
                hf[2 * q + 1] = __uint_as_float(u[q] & 0xffff0000u);
            }
        }
        float p = 0.0f;
        #pragma unroll
        for (int o = 0; o < O_; ++o) p = fmaf(hf[o], vr[o], p);
        pb[il][c] = p;
        __syncthreads();
        // local softmax over the 10 logits of row il (same order per thread)
        float pv[C_];
        #pragma unroll
        for (int q = 0; q < C_; ++q) pv[q] = pb[il][q];
        float m = pv[0];
        #pragma unroll
        for (int q = 1; q < C_; ++q) m = fmaxf(m, pv[q]);
        float sum = 0.0f;
        #pragma unroll
        for (int q = 0; q < C_; ++q) sum += __expf(pv[q] - m);
        const float route = __expf(p - m) * __builtin_amdgcn_rcpf(sum);
        #pragma unroll
        for (int o = 0; o < O_; ++o) sacc[o] = fmaf(route, hf[o], sacc[o]);
        __syncthreads();   // WAR: pb overwritten next batch
    }

    #pragma unroll
    for (int o = 0; o < O_; ++o) sr[il][c * O_ + o] = sacc[o];
    __syncthreads();
    if (tid < CO_) {
        float s = 0.0f;
        #pragma unroll
        for (int k = 0; k < 32; ++k) s += sr[k][tid];
        sPartR[((size_t)ic * B_ + b) * CO_ + tid] = s;
    }
}

// ---------------------------------------------------------------------------
// K_squash: reduce partials over chunks (4-way split), squash, write
// dst = (prev ? prev : 0) + v   (veff chain; prev=null for the final output).
// ---------------------------------------------------------------------------
__global__ __launch_bounds__(640) void k_squash(
    const float* __restrict__ sPart,   // [nchunk][B][CO]
    int nchunk, float scale,
    const float* __restrict__ prev,    // [B,CO] or null
    float* __restrict__ dst)           // [B,CO]
{
    __shared__ float red[4][CO_];
    const int b = blockIdx.x, tid = threadIdx.x;
    const int q = tid / CO_;           // 0..3
    const int co = tid % CO_;
    float s = 0.0f;
    for (int k = q; k < nchunk; k += 4)
        s += sPart[((size_t)k * B_ + b) * CO_ + co];
    red[q][co] = s;
    __syncthreads();
    if (tid < CO_) {
        s = (red[0][co] + red[1][co]) + (red[2][co] + red[3][co]);
        s *= scale;
        float n2 = s * s;
        n2 += __shfl_xor(n2, 1);
        n2 += __shfl_xor(n2, 2);
        n2 += __shfl_xor(n2, 4);
        n2 += __shfl_xor(n2, 8);
        const float sc = n2 / ((1.0f + n2) * sqrtf(n2 + EPS_));
        const float v = s * sc;
        dst[(size_t)b * CO_ + co] = (prev ? prev[(size_t)b * CO_ + co] : 0.0f) + v;
    }
}

// ---------------------------------------------------------------------------
// Fallback: fully fused single kernel (R1 version, ~402 us) if ws too small
// ---------------------------------------------------------------------------
#define THREADS 640
#define ILG 8
#define SUBI 4
#define CHUNK (ILG*SUBI)
#define NITER (I_/CHUNK)

__global__ __launch_bounds__(THREADS) void capsule_routing_kernel(
    const float* __restrict__ x, const float* __restrict__ W,
    float* __restrict__ out)
{
    __shared__ float bias[I_ * C_];
    __shared__ float spart[ILG][C_ * O_];
    __shared__ float sv[C_ * O_];
    __shared__ float vv[C_ * O_];
    __shared__ float ech[CHUNK][C_];
    __shared__ float scale[C_];

    const int b   = blockIdx.x;
    const int tid = threadIdx.x;
    for (int j = tid; j < I_ * C_; j += THREADS) bias[j] = 0.0f;
    const int il = tid / 80;
    const int rr = tid % 80;
    const int c  = rr / 8;
    const int o2 = rr % 8;
    const int o0 = o2 * 2;
    const float* xb = x + (size_t)b * I_ * D_;
    const float2* W2 = (const float2*)W;
    __syncthreads();
    {
        float acc0 = 0.0f, acc1 = 0.0f;
        for (int it = 0; it < NITER; ++it) {
            #pragma unroll
            for (int sub = 0; sub < SUBI; ++sub) {
                const int i = it * CHUNK + sub * ILG + il;
                const float* xi = xb + i * D_;
                const float2* wp = W2 + (i * C_ + c) * (D_ * O_ / 2) + o2;
                float h0 = 0.0f, h1 = 0.0f;
                #pragma unroll
                for (int d = 0; d < D_; ++d) {
                    float2 w = wp[d * (O_ / 2)];
                    float xv = xi[d];
                    h0 = fmaf(xv, w.x, h0);
                    h1 = fmaf(xv, w.y, h1);
                }
                acc0 += h0; acc1 += h1;
            }
        }
        spart[il][c * O_ + o0]     = acc0;
        spart[il][c * O_ + o0 + 1] = acc1;
    }
    __syncthreads();
    if (tid < C_ * O_) {
        float s = 0.0f;
        #pragma unroll
        for (int k = 0; k < ILG; ++k) s += spart[k][tid];
        sv[tid] = s * (1.0f / C_);
    }
    __syncthreads();
    if (tid < C_) {
        float n2 = 0.0f;
        #pragma unroll
        for (int o = 0; o < O_; ++o) { float t = sv[tid * O_ + o]; n2 = fmaf(t, t, n2); }
        scale[tid] = n2 / ((1.0f + n2) * sqrtf(n2 + EPS_));
    }
    __syncthreads();
    if (tid < C_ * O_) vv[tid] = sv[tid] * scale[tid / O_];
    __syncthreads();
    for (int pass = 1; pass < 3; ++pass) {
        float sa0 = 0.0f, sa1 = 0.0f;
        for (int it = 0; it < NITER; ++it) {
            float h0s[SUBI], h1s[SUBI];
            const float v0 = vv[c * O_ + o0];
            const float v1 = vv[c * O_ + o0 + 1];
            #pragma unroll
            for (int sub = 0; sub < SUBI; ++sub) {
                const int i = it * CHUNK + sub * ILG + il;
                const float* xi = xb + i * D_;
                const float2* wp = W2 + (i * C_ + c) * (D_ * O_ / 2) + o2;
                float h0 = 0.0f, h1 = 0.0f;
                #pragma unroll
                for (int d = 0; d < D_; ++d) {
                    float2 w = wp[d * (O_ / 2)];
                    float xv = xi[d];
                    h0 = fmaf(xv, w.x, h0);
                    h1 = fmaf(xv, w.y, h1);
                }
                h0s[sub] = h0; h1s[sub] = h1;
                float p = h0 * v0 + h1 * v1;
                p += __shfl_xor(p, 1);
                p += __shfl_xor(p, 2);
                p += __shfl_xor(p, 4);
                if (o2 == 0) bias[i * C_ + c] += p;
            }
            __syncthreads();
            if (tid < CHUNK * C_) {
                const int il2 = tid / C_, cc = tid % C_;
                const int i = it * CHUNK + il2;
                float m = -1e30f;
                #pragma unroll
                for (int k = 0; k < C_; ++k) m = fmaxf(m, bias[i * C_ + k]);
                ech[il2][cc] = __expf(bias[i * C_ + cc] - m);
            }
            __syncthreads();
            #pragma unroll
            for (int sub = 0; sub < SUBI; ++sub) {
                const int icx = sub * ILG + il;
                float sum = 0.0f;
                #pragma unroll
                for (int k = 0; k < C_; ++k) sum += ech[icx][k];
                const float route = ech[icx][c] / sum;
                sa0 = fmaf(route, h0s[sub], sa0);
                sa1 = fmaf(route, h1s[sub], sa1);
            }
            __syncthreads();
        }
        spart[il][c * O_ + o0]     = sa0;
        spart[il][c * O_ + o0 + 1] = sa1;
        __syncthreads();
        if (tid < C_ * O_) {
            float s = 0.0f;
            #pragma unroll
            for (int k = 0; k < ILG; ++k) s += spart[k][tid];
            sv[tid] = s;
        }
        __syncthreads();
        if (tid < C_) {
            float n2 = 0.0f;
            #pragma unroll
            for (int o = 0; o < O_; ++o) { float t = sv[tid * O_ + o]; n2 = fmaf(t, t, n2); }
            scale[tid] = n2 / ((1.0f + n2) * sqrtf(n2 + EPS_));
        }
        __syncthreads();
        if (tid < C_ * O_) vv[tid] = sv[tid] * scale[tid / O_];
        __syncthreads();
    }
    if (tid < C_ * O_) out[(size_t)b * C_ * O_ + tid] = vv[tid];
}

// ---------------------------------------------------------------------------
extern "C" void kernel_launch(void* const* d_in, const int* in_sizes, int n_in,
                              void* d_out, int out_size, void* d_ws, size_t ws_size,
                              hipStream_t stream) {
    (void)in_sizes; (void)n_in; (void)out_size;
    const float* x = (const float*)d_in[0];
    const float* W = (const float*)d_in[1];
    float* out = (float*)d_out;

    const size_t hat_b  = (size_t)B_ * I_ * CO_ * sizeof(__hip_bfloat16); // 94.4 MB
    const size_t sp1_b  = (size_t)NIC1 * B_ * CO_ * sizeof(float);        // 11.8 MB
    const size_t spr_b  = (size_t)NIC3 * B_ * CO_ * sizeof(float);        //  1.5 MB
    const size_t v_b    = (size_t)B_ * CO_ * sizeof(float);               //  160 KB
    const size_t need   = hat_b + sp1_b + spr_b + 2 * v_b;                // ~108 MB

    if (ws_size >= need) {
        char* p = (char*)d_ws;
        __hip_bfloat16* hat = (__hip_bfloat16*)p;  p += hat_b;
        float* sPart1 = (float*)p;                 p += sp1_b;
        float* sPartR = (float*)p;                 p += spr_b;
        float* veff1  = (float*)p;                 p += v_b;
        float* veff2  = (float*)p;

        k1_hat<<<dim3(NIC1, NBT), T1, 0, stream>>>(x, W, hat, sPart1);
        k_squash<<<B_, 640, 0, stream>>>(sPart1, NIC1, 1.0f / C_, nullptr, veff1);
        k_route<<<dim3(NIC3, B_), T3, 0, stream>>>(hat, veff1, sPartR);
        k_squash<<<B_, 640, 0, stream>>>(sPartR, NIC3, 1.0f, veff1, veff2);
        k_route<<<dim3(NIC3, B_), T3, 0, stream>>>(hat, veff2, sPartR);
        k_squash<<<B_, 640, 0, stream>>>(sPartR, NIC3, 1.0f, nullptr, out);
    } else {
        capsule_routing_kernel<<<B_, THREADS, 0, stream>>>(x, W, out);
    }
}